// Round 8
// baseline (467.120 us; speedup 1.0000x reference)
//
#include <hip/hip_runtime.h>
#include <hip/hip_bf16.h>
#include <math.h>

#define EPSF 1e-5f

typedef __attribute__((ext_vector_type(8))) short bf16x8;
typedef __attribute__((ext_vector_type(4))) float f32x4;

__device__ __forceinline__ void gld16(const void* g, void* l) {
  __builtin_amdgcn_global_load_lds(
      (const __attribute__((address_space(1))) unsigned int*)g,
      (__attribute__((address_space(3))) unsigned int*)l, 16, 0, 0);
}

// ---------------- fused instance-norm stats + normalize + transpose + hi/lo split ----------------
// x[b]: [512,32] -> XNB[b*32+c][l' hi | l'+512 lo]; also writes mean/std [B,32]
__global__ __launch_bounds__(256) void prep_kernel(
    const float* __restrict__ x, float* __restrict__ meanp,
    float* __restrict__ stdp, __hip_bfloat16* __restrict__ xnb)
{
  __shared__ float xs[512 * 33];
  __shared__ float red[8][32];
  __shared__ float red2[8][32];
  __shared__ float sm[32];
  __shared__ float srr[32];
  int b = blockIdx.x, tid = threadIdx.x;
  const float* xb = x + (size_t)b * 16384;
#pragma unroll
  for (int i = 0; i < 16; ++i) {
    int idx4 = tid + i * 256;
    int l = idx4 >> 3, c0 = (idx4 & 7) * 4;
    float4 v = *(const float4*)(xb + idx4 * 4);
    xs[l * 33 + c0 + 0] = v.x;
    xs[l * 33 + c0 + 1] = v.y;
    xs[l * 33 + c0 + 2] = v.z;
    xs[l * 33 + c0 + 3] = v.w;
  }
  __syncthreads();
  int c = tid & 31, ls = tid >> 5;
  float s = 0.f, s2 = 0.f;
  for (int l = ls; l < 512; l += 8) {
    float v = xs[l * 33 + c];
    s += v; s2 += v * v;
  }
  red[ls][c] = s; red2[ls][c] = s2;
  __syncthreads();
  if (ls == 0) {
#pragma unroll
    for (int i = 1; i < 8; ++i) { s += red[i][c]; s2 += red2[i][c]; }
    float m = s * (1.f / 512.f);
    float var = s2 * (1.f / 512.f) - m * m;
    float sd = sqrtf(var + EPSF);
    meanp[b * 32 + c] = m;
    stdp[b * 32 + c] = sd;
    sm[c] = m;
    srr[c] = 1.f / sd;
  }
  __syncthreads();
  for (int cc = 0; cc < 32; ++cc) {
    float m = sm[cc];
    float r = srr[cc];
    int l = tid * 2;
    float v0 = (xs[l * 33 + cc] - m) * r;
    float v1 = (xs[(l + 1) * 33 + cc] - m) * r;
    __hip_bfloat16 h0 = __float2bfloat16(v0);
    __hip_bfloat16 h1 = __float2bfloat16(v1);
    union { __hip_bfloat16 h[2]; unsigned int u; } H, L;
    H.h[0] = h0; H.h[1] = h1;
    L.h[0] = __float2bfloat16(v0 - __bfloat162float(h0));
    L.h[1] = __float2bfloat16(v1 - __bfloat162float(h1));
    unsigned int* dst =
        (unsigned int*)((unsigned short*)xnb + ((size_t)(b * 32 + cc)) * 1024 + l);
    dst[0] = H.u;
    dst[256] = L.u;
  }
}

// ---------------- Fourier-mask -> time-domain filter taps (duplicated) ----------------
// R6: table-driven (sig[257]+ctab[512] in LDS), 64 blocks; was 52.7us @ 8 blocks.
__global__ __launch_bounds__(256) void kfilt_kernel(
    const float* __restrict__ mw, float* __restrict__ kf)
{
  __shared__ float sig[257];
  __shared__ float ctab[512];
  __shared__ float red[8][33];
  int bid = blockIdx.x, tid = threadIdx.x;
  int nb = bid >> 4, t0 = (bid & 15) * 32;
  const float* m = mw + nb * 257;
  for (int i = tid; i < 257; i += 256) sig[i] = 1.f / (1.f + expf(-m[i]));
  ctab[tid]       = cosf(6.28318530717958647f * (float)tid * (1.f / 512.f));
  ctab[tid + 256] = cosf(6.28318530717958647f * (float)(tid + 256) * (1.f / 512.f));
  __syncthreads();
  int tl = tid & 31, fl = tid >> 5;
  int t = t0 + tl;
  float acc = 0.f;
#pragma unroll
  for (int j = 0; j < 32; ++j) {
    int f = fl * 32 + j;
    if (f >= 1) {
      int tf = (t * f) & 511;
      acc += 2.f * sig[f] * ctab[tf];
    }
  }
  red[fl][tl] = acc;
  __syncthreads();
  if (fl == 0) {
    float a = red[0][tl];
#pragma unroll
    for (int i = 1; i < 8; ++i) a += red[i][tl];
    float s0 = sig[0], sN = sig[256];
    a += s0 + ((t & 1) ? -sN : sN);
    float kv = a * (1.f / 512.f);
    kf[nb * 1024 + t] = kv;
    kf[nb * 1024 + t + 512] = kv;
  }
}

// ---------------- circulant matrix build: CM[nb][l][l' | l'+512] bf16 hi|lo ----------------
__global__ __launch_bounds__(256) void cmat_kernel(
    const float* __restrict__ kf, __hip_bfloat16* __restrict__ cm)
{
  int t = threadIdx.x;
  int row = blockIdx.x * 4 + (t >> 6);
  int nb = row >> 9, l = row & 511;
  int lp0 = (t & 63) * 8;
  union { __hip_bfloat16 h[8]; uint4 u; } H, L;
#pragma unroll
  for (int j = 0; j < 8; ++j) {
    float v = kf[nb * 1024 + 512 + l - (lp0 + j)];
    __hip_bfloat16 h = __float2bfloat16(v);
    H.h[j] = h;
    L.h[j] = __float2bfloat16(v - __bfloat162float(h));
  }
  unsigned short* dst = (unsigned short*)cm + (size_t)row * 1024 + lp0;
  *(uint4*)dst = H.u;
  *(uint4*)(dst + 512) = L.u;
}

// ---------------- fp32 -> bf16 hi/lo split: in [rows,K] -> out [rows,2K] ----------------
__global__ __launch_bounds__(256) void split_kernel(
    const float* __restrict__ in, __hip_bfloat16* __restrict__ out, int ks)
{
  int t = blockIdx.x * 256 + threadIdx.x;
  long long idx = (long long)t * 4;
  int K = 1 << ks;
  long long r = idx >> ks;
  int k = (int)(idx & (K - 1));
  float4 v = *(const float4*)(in + idx);
  float vv[4] = {v.x, v.y, v.z, v.w};
  union { __hip_bfloat16 h[4]; uint2 u; } H, L;
#pragma unroll
  for (int u = 0; u < 4; ++u) {
    H.h[u] = __float2bfloat16(vv[u]);
    L.h[u] = __float2bfloat16(vv[u] - __bfloat162float(H.h[u]));
  }
  unsigned short* ob = (unsigned short*)out + (r << (ks + 1)) + k;
  *(uint2*)ob = H.u;
  *(uint2*)(ob + K) = L.u;
}

// ---------------- fp32 -> bf16 hi-only cast (dense, single source) ----------------
__global__ __launch_bounds__(256) void splith_kernel(
    const float* __restrict__ in, __hip_bfloat16* __restrict__ out)
{
  long long idx = ((long long)blockIdx.x * 256 + threadIdx.x) * 4;
  float4 v = *(const float4*)(in + idx);
  union { __hip_bfloat16 h[4]; uint2 u; } H;
  H.h[0] = __float2bfloat16(v.x);
  H.h[1] = __float2bfloat16(v.y);
  H.h[2] = __float2bfloat16(v.z);
  H.h[3] = __float2bfloat16(v.w);
  *(uint2*)((unsigned short*)out + idx) = H.u;
}

// ---------------- fused hi-only cast of 4 weights into contiguous dest ----------------
// ranges (float4 units): enc_w2 524288 | wxh 262144 | dec_w1 524288 | dec_w2 2097152
__global__ __launch_bounds__(256) void splith4_kernel(
    const float* __restrict__ s0, const float* __restrict__ s1,
    const float* __restrict__ s2, const float* __restrict__ s3,
    __hip_bfloat16* __restrict__ out)
{
  long long i4 = (long long)blockIdx.x * 256 + threadIdx.x;  // 3,407,872 total
  const float* src;
  long long lo;
  if (i4 < 524288)        { src = s0; lo = i4; }
  else if (i4 < 786432)   { src = s1; lo = i4 - 524288; }
  else if (i4 < 1310720)  { src = s2; lo = i4 - 786432; }
  else                    { src = s3; lo = i4 - 1310720; }
  float4 v = ((const float4*)src)[lo];
  union { __hip_bfloat16 h[4]; uint2 u; } H;
  H.h[0] = __float2bfloat16(v.x);
  H.h[1] = __float2bfloat16(v.y);
  H.h[2] = __float2bfloat16(v.z);
  H.h[3] = __float2bfloat16(v.w);
  *(uint2*)((unsigned short*)out + i4 * 4) = H.u;
}

// ---------------- transpose + split: WT2[nb][col][hi 512 | lo 512] = whh^T ----------------
__global__ __launch_bounds__(256) void tsplit_kernel(
    const float* __restrict__ w, __hip_bfloat16* __restrict__ wt2)
{
  __shared__ float ts[64][65];
  int bx = blockIdx.x, by = blockIdx.y, nb = blockIdx.z;
  int t = threadIdx.x;
  int tr = t >> 4, c0 = (t & 15) * 4;
  const float* wb = w + (size_t)nb * 262144;
#pragma unroll
  for (int k = 0; k < 4; ++k) {
    int r = tr + k * 16;
    float4 v = *(const float4*)(wb + (size_t)(by * 64 + r) * 512 + bx * 64 + c0);
    ts[r][c0 + 0] = v.x; ts[r][c0 + 1] = v.y;
    ts[r][c0 + 2] = v.z; ts[r][c0 + 3] = v.w;
  }
  __syncthreads();
  unsigned short* ob = (unsigned short*)wt2 + (size_t)nb * 524288;
#pragma unroll
  for (int k = 0; k < 4; ++k) {
    int r = tr + k * 16;
    float vv[4] = {ts[c0][r], ts[c0 + 1][r], ts[c0 + 2][r], ts[c0 + 3][r]};
    union { __hip_bfloat16 h[4]; uint2 u; } H, L;
#pragma unroll
    for (int j = 0; j < 4; ++j) {
      H.h[j] = __float2bfloat16(vv[j]);
      L.h[j] = __float2bfloat16(vv[j] - __bfloat162float(H.h[j]));
    }
    size_t row = (size_t)(bx * 64 + r);
    *(uint2*)(ob + row * 1024 + by * 64 + c0) = H.u;
    *(uint2*)(ob + row * 1024 + 512 + by * 64 + c0) = L.u;
  }
}

// ---------------- split-bf16 MFMA GEMM, compile-time NSEG/NCH, tiled by template ----------------
// Tile = (32*NI) x (32*NJ), 256 thr (4 waves, 2x2). 16x16x32 bf16 MFMA.
// R8: per-site NCH, empirically anchored (A/B across R4-R7):
//     enc1 (streams 32MB XIH from HBM/L3, K=2048): NCH=2 (57.6us) beats NCH=4 (90.8us)
//       -> staging latency-exposed, small bursts + anti-phase blocks win.
//     dec2 (L2-resident operands after XCD swizzle): NCH=4 beat NCH=2 by ~25us
//       (R6->R7 algebra: enc1 saved 33 but total only -7.5).
//     <4,2> sites: NCH=4 (drove R5's net gain). conv/NSEG3: NCH=2.
// NSEG1: Ahi*Bhi   NSEG2: Ahi*(Bhi+Blo)   NSEG3: + Alo*Bhi
// swapg=1: blockIdx.x indexes M-tiles (XCD-local A stripes)
// R2: chunked-bijective XCD swizzle (T1): lid -> (lid%8)*(nwg/8)+lid/8
//     (FETCH 82->41MB measured at enc1). Identity fallback when nwg%8 != 0.
// z-batching two-level: off = (bz/nz2)*b?1 + (bz%nz2)*b?2 (element units).
// mode 0: normal epilogue (bias, Add fp32, relu, Cf fp32, C2 hi at ldc2 [+lo at loC2 if !=0])
// mode 1: XIH scatter (conv output, hi only)
// mode 2: Cf normal + C2 as XP concat [b][f*512+n | 4096+f*512+n]
template<int NI, int NJ, int NSEG, int NCH>
__global__ __launch_bounds__(256) void gemm_mfma(
    const __hip_bfloat16* __restrict__ A_, int ldA, long long bA1, long long bA2, int loA,
    const __hip_bfloat16* __restrict__ B_, int ldB, long long bB1, long long bB2, int loB,
    const float* __restrict__ bias, long long bBias1, long long bBias2,
    const float* __restrict__ Add, int ldadd, long long bAdd1, long long bAdd2,
    float* __restrict__ Cf, int ldcf, long long bCf1, long long bCf2,
    __hip_bfloat16* __restrict__ C2, int ldc2, int loC2, long long bC21, long long bC22,
    int nz2, int M, int N, int K, int relu, int mode, int swapg)
{
  constexpr bool three = (NSEG == 3);
  constexpr bool btwo = (NSEG >= 2);
  constexpr int CHA = 32 * NI * 32;   // chunk stride (shorts) for A buffers
  constexpr int CHB = 32 * NJ * 32;   // chunk stride (shorts) for B buffers
  __shared__ short sAh[NCH * 32 * NI * 32];
  __shared__ short sAl[three ? NCH * 32 * NI * 32 : 1];
  __shared__ short sBh[NCH * 32 * NJ * 32];
  __shared__ short sBl[btwo ? NCH * 32 * NJ * 32 : 1];

  // ---- R2: XCD-chunked block-index remap (pure reindex, no numeric effect) ----
  int gx = gridDim.x, gy = gridDim.y;
  int nwg = gx * gy * (int)gridDim.z;
  int lid = (int)blockIdx.x + gx * ((int)blockIdx.y + gy * (int)blockIdx.z);
  if ((nwg & 7) == 0) lid = (lid & 7) * (nwg >> 3) + (lid >> 3);
  int bz  = lid / (gx * gy);
  int rrm = lid - bz * (gx * gy);
  int byq = rrm / gx;
  int bxq = rrm - byq * gx;

  int z1 = bz / nz2, z2 = bz % nz2;
  const short* Ab = (const short*)A_ + (long long)z1 * bA1 + (long long)z2 * bA2;
  const short* Bb = (const short*)B_ + (long long)z1 * bB1 + (long long)z2 * bB2;
  int tid = threadIdx.x, wave = tid >> 6, lane = tid & 63;
  int bxv = swapg ? byq : bxq;
  int byv = swapg ? bxq : byq;
  int bm = byv * (32 * NI), bn = bxv * (32 * NJ);
  int wrow = (wave >> 1) * (16 * NI), wcol = (wave & 1) * (16 * NJ);

  int sr = lane >> 2;
  int qg = (lane & 3) ^ (sr & 3);
  int arA = wave * 8 * NI;
  int arB = wave * 8 * NJ;

  f32x4 acc[NI][NJ];
#pragma unroll
  for (int i = 0; i < NI; ++i)
#pragma unroll
    for (int j = 0; j < NJ; ++j)
      acc[i][j] = (f32x4){0.f, 0.f, 0.f, 0.f};

  int frow = lane & 15;
  int fq = lane >> 4;
  int aoffs[NI], boffs[NJ];
#pragma unroll
  for (int i = 0; i < NI; ++i) {
    int ra = wrow + 16 * i + frow;
    aoffs[i] = ra * 32 + ((fq ^ (ra & 3)) << 3);
  }
#pragma unroll
  for (int j = 0; j < NJ; ++j) {
    int rb = wcol + 16 * j + frow;
    boffs[j] = rb * 32 + ((fq ^ (rb & 3)) << 3);
  }

  const short* Ah = Ab + (long long)(bm + arA + sr) * ldA + qg * 8;
  const short* Al = Ah + loA;
  const short* Bh = Bb + (long long)(bn + arB + sr) * ldB + qg * 8;
  const short* Bl = Bh + loB;

  for (int ko = 0; ko < K; ko += 32 * NCH) {
    // stage NCH 32-K chunks (chunk ch at +32*ch K, into LDS offset ch*CHA/CHB)
#pragma unroll
    for (int cc = 0; cc < NI / 2; ++cc) {
#pragma unroll
      for (int ch = 0; ch < NCH; ++ch) {
        gld16(Ah + ko + ch * 32 + cc * 16 * ldA, &sAh[ch * CHA + (arA + cc * 16) * 32]);
        if constexpr (three)
          gld16(Al + ko + ch * 32 + cc * 16 * ldA, &sAl[ch * CHA + (arA + cc * 16) * 32]);
      }
    }
#pragma unroll
    for (int cc = 0; cc < NJ / 2; ++cc) {
#pragma unroll
      for (int ch = 0; ch < NCH; ++ch) {
        gld16(Bh + ko + ch * 32 + cc * 16 * ldB, &sBh[ch * CHB + (arB + cc * 16) * 32]);
        if constexpr (btwo)
          gld16(Bl + ko + ch * 32 + cc * 16 * ldB, &sBl[ch * CHB + (arB + cc * 16) * 32]);
      }
    }
    __syncthreads();
#pragma unroll
    for (int h = 0; h < NCH; ++h) {
      const int oA = h * CHA, oB = h * CHB;
      bf16x8 ah[NI], al[NI], bh[NJ], bl[NJ];
#pragma unroll
      for (int i = 0; i < NI; ++i) ah[i] = *(const bf16x8*)&sAh[oA + aoffs[i]];
#pragma unroll
      for (int j = 0; j < NJ; ++j) bh[j] = *(const bf16x8*)&sBh[oB + boffs[j]];
      if constexpr (btwo) {
#pragma unroll
        for (int j = 0; j < NJ; ++j) bl[j] = *(const bf16x8*)&sBl[oB + boffs[j]];
      }
      if constexpr (three) {
#pragma unroll
        for (int i = 0; i < NI; ++i) al[i] = *(const bf16x8*)&sAl[oA + aoffs[i]];
      }
#pragma unroll
      for (int i = 0; i < NI; ++i)
#pragma unroll
        for (int j = 0; j < NJ; ++j) {
          acc[i][j] = __builtin_amdgcn_mfma_f32_16x16x32_bf16(ah[i], bh[j], acc[i][j], 0, 0, 0);
          if constexpr (btwo)
            acc[i][j] = __builtin_amdgcn_mfma_f32_16x16x32_bf16(ah[i], bl[j], acc[i][j], 0, 0, 0);
          if constexpr (three)
            acc[i][j] = __builtin_amdgcn_mfma_f32_16x16x32_bf16(al[i], bh[j], acc[i][j], 0, 0, 0);
        }
    }
    __syncthreads();
  }

  short* c2z = C2 ? (short*)C2 + (long long)z1 * bC21 + (long long)z2 * bC22 : nullptr;

  if (mode == 1) {
    // m = l (0..511), n = b*32+c -> XIH row = b*8 + l/64, col = (l%64)*32 + c
#pragma unroll
    for (int j = 0; j < NJ; ++j) {
      int n = bn + wcol + 16 * j + frow;
      int bidx = n >> 5, c = n & 31;
#pragma unroll
      for (int i = 0; i < NI; ++i)
#pragma unroll
        for (int r = 0; r < 4; ++r) {
          int m = bm + wrow + 16 * i + fq * 4 + r;
          int row = bidx * 8 + (m >> 6);
          int col = (m & 63) * 32 + c;
          ((__hip_bfloat16*)c2z)[(long long)row * 2048 + col] =
              __float2bfloat16(acc[i][j][r]);
        }
    }
    return;
  }

  const float* biasz = bias ? bias + (long long)z1 * bBias1 + (long long)z2 * bBias2 : nullptr;
  const float* addz  = Add  ? Add  + (long long)z1 * bAdd1  + (long long)z2 * bAdd2  : nullptr;
  float* cfz = Cf ? Cf + (long long)z1 * bCf1 + (long long)z2 * bCf2 : nullptr;

#pragma unroll
  for (int j = 0; j < NJ; ++j) {
    int n = bn + wcol + 16 * j + frow;
    float bv = biasz ? biasz[n] : 0.f;
#pragma unroll
    for (int i = 0; i < NI; ++i) {
#pragma unroll
      for (int r = 0; r < 4; ++r) {
        int m = bm + wrow + 16 * i + fq * 4 + r;
        float v = acc[i][j][r] + bv;
        if (addz) v += addz[(long long)m * ldadd + n];
        if (relu) v = fmaxf(v, 0.f);
        if (cfz) cfz[(long long)m * ldcf + n] = v;
        if (c2z) {
          __hip_bfloat16 h = __float2bfloat16(v);
          if (mode == 2) {
            __hip_bfloat16 l = __float2bfloat16(v - __bfloat162float(h));
            long long off = (long long)(m >> 3) * 8192 + (m & 7) * 512 + n;
            ((__hip_bfloat16*)c2z)[off] = h;
            ((__hip_bfloat16*)c2z)[off + 4096] = l;
          } else {
            ((__hip_bfloat16*)c2z)[(long long)m * ldc2 + n] = h;
            if (loC2) {
              __hip_bfloat16 l = __float2bfloat16(v - __bfloat162float(h));
              ((__hip_bfloat16*)c2z)[(long long)m * ldc2 + loC2 + n] = l;
            }
          }
        }
      }
    }
  }
}

// ---------------- LayerNorm over 512, writes bf16 hi-only [row, 512] ----------------
__global__ __launch_bounds__(256) void ln_kernel(
    const float* __restrict__ p, const float* __restrict__ g,
    const float* __restrict__ bb, __hip_bfloat16* __restrict__ p2)
{
  int row = blockIdx.x;              // NB*B*4 = 4096
  int nb = row >> 10;
  const float* pr = p + (size_t)row * 512;
  int tid = threadIdx.x;
  float v0 = pr[tid], v1 = pr[tid + 256];
  float s = v0 + v1, s2 = v0 * v0 + v1 * v1;
#pragma unroll
  for (int o = 32; o > 0; o >>= 1) {
    s += __shfl_down(s, o);
    s2 += __shfl_down(s2, o);
  }
  __shared__ float rs[4];
  __shared__ float rs2[4];
  int w = tid >> 6;
  if ((tid & 63) == 0) { rs[w] = s; rs2[w] = s2; }
  __syncthreads();
  s = rs[0] + rs[1] + rs[2] + rs[3];
  s2 = rs2[0] + rs2[1] + rs2[2] + rs2[3];
  float mval = s * (1.f / 512.f);
  float var = s2 * (1.f / 512.f) - mval * mval;
  float r = 1.f / sqrtf(var + EPSF);
  const float* gn = g + nb * 512;
  const float* bn = bb + nb * 512;
  float y0 = (v0 - mval) * r * gn[tid] + bn[tid];
  float y1 = (v1 - mval) * r * gn[tid + 256] + bn[tid + 256];
  __hip_bfloat16* o2 = p2 + (size_t)nb * 524288 + (size_t)(row & 1023) * 512;
  o2[tid] = __float2bfloat16(y0);
  o2[tid + 256] = __float2bfloat16(y1);
}

// ---------------- final: out = (sum_nb deco) * std + mean ----------------
__global__ __launch_bounds__(256) void final_kernel(
    const float* __restrict__ deco, const float* __restrict__ meanp,
    const float* __restrict__ stdp, float* __restrict__ out)
{
  int t = blockIdx.x * 256 + threadIdx.x;
  int b = t >> 11;
  int r = t & 2047;
  int p = (r >> 3) & 63;
  int cq = r & 7;
  size_t base = ((size_t)(b * 4 + (r >> 9))) * 2048 + p * 32 + cq * 4;
  const size_t nbs = 1024ull * 2048ull;
  float4 a0 = *(const float4*)(deco + base);
  float4 a1 = *(const float4*)(deco + nbs + base);
  float4 a2 = *(const float4*)(deco + 2 * nbs + base);
  float4 a3 = *(const float4*)(deco + 3 * nbs + base);
  float4 m4 = *(const float4*)(meanp + b * 32 + cq * 4);
  float4 s4 = *(const float4*)(stdp + b * 32 + cq * 4);
  float4 o;
  o.x = (a0.x + a1.x + a2.x + a3.x) * s4.x + m4.x;
  o.y = (a0.y + a1.y + a2.y + a3.y) * s4.y + m4.y;
  o.z = (a0.z + a1.z + a2.z + a3.z) * s4.z + m4.z;
  o.w = (a0.w + a1.w + a2.w + a3.w) * s4.w + m4.w;
  *(float4*)(out + (size_t)t * 4) = o;
}

extern "C" void kernel_launch(void* const* d_in, const int* in_sizes, int n_in,
                              void* d_out, int out_size, void* d_ws, size_t ws_size,
                              hipStream_t stream) {
  const float* x_enc  = (const float*)d_in[0];
  const float* mask_w = (const float*)d_in[4];
  const float* enc_w1 = (const float*)d_in[5];
  const float* enc_b1 = (const float*)d_in[6];
  const float* enc_w2 = (const float*)d_in[7];
  const float* enc_b2 = (const float*)d_in[8];
  const float* wxh    = (const float*)d_in[9];
  const float* whh    = (const float*)d_in[10];
  const float* ln_g   = (const float*)d_in[11];
  const float* ln_b   = (const float*)d_in[12];
  const float* dec_w1 = (const float*)d_in[13];
  const float* dec_b1 = (const float*)d_in[14];
  const float* dec_w2 = (const float*)d_in[15];
  const float* dec_b2 = (const float*)d_in[16];
  float* out = (float*)d_out;

  typedef __hip_bfloat16 bf;
  char* W = (char*)d_ws;
  float* MEAN = (float*)(W);
  float* STD  = (float*)(W + 32768);
  float* KF   = (float*)(W + 98304);
  char* B0 = W + 131072;
  // ---- layout (MB offsets from B0); peak 112 MB; lifetimes as R9 (verified) ----
  bf* XIH   = (bf*)(B0);                    // [0,32)    dead after enc1
  bf* XNB   = (bf*)(B0 + 33554432);         // [32,48)   dead after conv
  bf* CM    = (bf*)(B0 + 50331648);         // [48,52)   dead after conv
  bf* WW    = (bf*)(B0 + 33554432);         // [32,48)   16MB hi, written post-conv, dead after enc1
  bf* ENCB2 = (bf*)(B0 + 67108864);         // [64,80)   16MB hi, dead after enc2
  // weight splits (after enc1; splith4 dest = [0,26) contiguous):
  bf* EW2   = (bf*)(B0);                    // [0,4)     4MB hi
  bf* WXH2  = (bf*)(B0 + 4194304);          // [4,6)     2MB hi
  bf* DW1   = (bf*)(B0 + 6291456);          // [6,10)    4MB hi, read at dec1
  bf* DW2   = (bf*)(B0 + 10485760);         // [10,26)   16MB hi, read at dec2
  bf* WSP   = (bf*)(B0 + 27262976);         // [26,30)   4MB hi|lo
  bf* W2SP  = (bf*)(B0 + 31457280);         // [30,34)   4MB hi|lo
  bf* WTSP  = (bf*)(B0 + 35651584);         // [34,38)   4MB hi|lo, dead after W2 GEMM
  bf* ENC22 = (bf*)(B0 + 39845888);         // [38,46)   8MB hi, dead after xp
  float* XP = (float*)(B0 + 48234496);      // [46,62)   fp32, dead after y-combine
  bf* XP2   = (bf*)(B0 + 67108864);         // [64,80)   hi|lo (ENCB2 dead), dead after y-combine
  float* YF = (float*)(B0 + 83886080);      // [80,88)   dead after Horner-3
  bf* Y2    = (bf*)(B0 + 92274688);         // [88,96)   hi|lo, dead after Horner-1
  bf* H2    = (bf*)(B0 + 100663296);        // [96,98)
  bf* H22   = (bf*)(B0 + 102760448);        // [98,100)
  bf* P12   = (bf*)(B0 + 104857600);        // [100,104)
  float* PREDS = (float*)(B0 + 109051904);  // [104,112)
  bf* PREDS2 = (bf*)(B0);                   // [0,4)     written at ln (EW2 dead)
  bf* DBUF2 = (bf*)(B0 + 83886080);         // [80,88)   dec1 out (YF dead)
  float* DECO = (float*)(B0 + 33554432);    // [32,64)   dec2 out (WTSP/ENC22/XP dead)

  prep_kernel<<<256, 256, 0, stream>>>(x_enc, MEAN, STD, XNB);
  kfilt_kernel<<<64, 256, 0, stream>>>(mask_w, KF);
  cmat_kernel<<<512, 256, 0, stream>>>(KF, CM);

  // conv as MFMA GEMM (pure bf16 hi, NSEG=1, NCH=2: grid 1024 = 4 blocks/CU, keep 32KB LDS)
  gemm_mfma<4, 4, 1, 2><<<dim3(64, 4, 4), 256, 0, stream>>>(
      CM, 1024, 524288LL, 0LL, 0, XNB, 1024, 0LL, 0LL, 0,
      nullptr, 0, 0, nullptr, 0, 0, 0, nullptr, 0, 0, 0,
      XIH, 0, 0, 4194304LL, 0LL, 1, 512, 8192, 512, 0, 1, 0);

  // enc1: M=2048 N=1024 K=2048, NSEG=1, NCH=2 (HBM-streaming site: NCH=4 regressed 57.6->90.8)
  splith_kernel<<<8192, 256, 0, stream>>>(enc_w1, WW);
  gemm_mfma<4, 4, 1, 2><<<dim3(16, 8, 4), 256, 0, stream>>>(
      XIH, 2048, 4194304LL, 0LL, 0, WW, 2048, 2097152LL, 0LL, 0,
      enc_b1, 1024LL, 0LL, nullptr, 0, 0, 0, nullptr, 0, 0, 0,
      ENCB2, 1024, 0, 2097152LL, 0LL, 1, 2048, 1024, 2048, 1, 0, 1);

  // fused weight casts (XIH dead now): enc_w2|wxh|dec_w1|dec_w2 -> [0,26)
  splith4_kernel<<<13312, 256, 0, stream>>>(enc_w2, wxh, dec_w1, dec_w2, EW2);
  split_kernel<<<1024, 256, 0, stream>>>(whh, WSP, 9);
  tsplit_kernel<<<dim3(8, 8, 4), 256, 0, stream>>>(whh, WTSP);

  // enc2: M=2048 N=512 K=1024, NSEG=1, NCH=4 (48KB LDS, 24KB burst); swapg
  gemm_mfma<4, 2, 1, 4><<<dim3(16, 8, 4), 256, 0, stream>>>(
      ENCB2, 1024, 2097152LL, 0LL, 0, EW2, 1024, 524288LL, 0LL, 0,
      enc_b2, 512LL, 0LL, nullptr, 0, 0, 0, nullptr, 0, 0, 0,
      ENC22, 512, 0, 1048576LL, 0LL, 1, 2048, 512, 1024, 0, 0, 1);

  // xp = enc2 @ wxh^T: NSEG=1, NCH=4; fp32 out + XP2 hi|lo-concat (mode 2); swapg
  gemm_mfma<4, 2, 1, 4><<<dim3(16, 8, 4), 256, 0, stream>>>(
      ENC22, 512, 1048576LL, 0LL, 0, WXH2, 512, 262144LL, 0LL, 0,
      nullptr, 0, 0, nullptr, 0, 0, 0, XP, 512, 1048576LL, 0LL,
      XP2, 0, 0, 2097152LL, 0LL, 1, 2048, 512, 512, 0, 2, 1);

  // W2 = W @ W (NSEG=3, NCH=2) -> split-out W2SP
  gemm_mfma<2, 2, 3, 2><<<dim3(8, 8, 4), 256, 0, stream>>>(
      WSP, 1024, 524288LL, 0LL, 512, WTSP, 1024, 524288LL, 0LL, 512,
      nullptr, 0, 0, nullptr, 0, 0, 0, nullptr, 0, 0, 0,
      W2SP, 1024, 512, 524288LL, 0LL, 1, 512, 512, 512, 0, 0, 0);

  // y_j = xp_{2j} @ W^T + xp_{2j+1}   (z1 = j, z2 = nb, 16 total), NSEG=3
  gemm_mfma<2, 2, 3, 2><<<dim3(8, 4, 16), 256, 0, stream>>>(
      XP2, 8192, 1024LL, 2097152LL, 4096, WSP, 1024, 0LL, 524288LL, 512,
      nullptr, 0, 0, XP + 512, 4096, 1024LL, 1048576LL,
      YF, 512, 524288LL, 131072LL,
      Y2, 1024, 512, 1048576LL, 262144LL, 4, 256, 512, 512, 0, 0, 0);

  // Horner with W2 (NSEG=3)
  gemm_mfma<2, 2, 3, 2><<<dim3(8, 4, 4), 256, 0, stream>>>(
      Y2, 1024, 0LL, 262144LL, 512, W2SP, 1024, 0LL, 524288LL, 512,
      nullptr, 0, 0, YF + 524288, 512, 0LL, 131072LL, nullptr, 0, 0, 0,
      H2, 1024, 512, 0LL, 262144LL, 4, 256, 512, 512, 0, 0, 0);
  gemm_mfma<2, 2, 3, 2><<<dim3(8, 4, 4), 256, 0, stream>>>(
      H2, 1024, 0LL, 262144LL, 512, W2SP, 1024, 0LL, 524288LL, 512,
      nullptr, 0, 0, YF + 1048576, 512, 0LL, 131072LL, nullptr, 0, 0, 0,
      H22, 1024, 512, 0LL, 262144LL, 4, 256, 512, 512, 0, 0, 0);
  gemm_mfma<2, 2, 3, 2><<<dim3(8, 4, 4), 256, 0, stream>>>(
      H22, 1024, 0LL, 262144LL, 512, W2SP, 1024, 0LL, 524288LL, 512,
      nullptr, 0, 0, YF + 1572864, 512, 0LL, 131072LL, nullptr, 0, 0, 0,
      H2, 1024, 512, 0LL, 262144LL, 4, 256, 512, 512, 0, 0, 0);

  // free-run A: p1 = h@W^T (z1=0), p2 = h@W2^T (z1=1), NSEG=3
  gemm_mfma<2, 2, 3, 2><<<dim3(8, 4, 8), 256, 0, stream>>>(
      H2, 1024, 0LL, 262144LL, 512, WSP, 1024, 2097152LL, 524288LL, 512,
      nullptr, 0, 0, nullptr, 0, 0, 0, PREDS, 2048, 512LL, 524288LL,
      P12, 1024, 512, 1048576LL, 262144LL, 4, 256, 512, 512, 0, 0, 0);
  // free-run B: p3 = p1@W2^T, p4 = p2@W2^T, NSEG=3
  gemm_mfma<2, 2, 3, 2><<<dim3(8, 4, 8), 256, 0, stream>>>(
      P12, 1024, 1048576LL, 262144LL, 512, W2SP, 1024, 0LL, 524288LL, 512,
      nullptr, 0, 0, nullptr, 0, 0, 0, PREDS + 1024, 2048, 512LL, 524288LL,
      nullptr, 0, 0, 0LL, 0LL, 4, 256, 512, 512, 0, 0, 0);

  ln_kernel<<<4096, 256, 0, stream>>>(PREDS, ln_g, ln_b, PREDS2);

  // dec1: M=1024 N=1024 K=512, NSEG=1, NCH=4 (48KB LDS)
  gemm_mfma<4, 2, 1, 4><<<dim3(16, 8, 4), 256, 0, stream>>>(
      PREDS2, 512, 524288LL, 0LL, 0, DW1, 512, 524288LL, 0LL, 0,
      dec_b1, 1024LL, 0LL, nullptr, 0, 0, 0, nullptr, 0, 0, 0,
      DBUF2, 1024, 0, 1048576LL, 0LL, 1, 1024, 1024, 512, 1, 0, 0);
  // dec2: M=1024 N=2048 K=1024, NSEG=1, NCH=4 (R8 restore: L2-resident operands,
  //       NCH=4 beat NCH=2 by ~25us per R6/R7 algebra); swapg + (8,16,4) L2-chunk grid
  gemm_mfma<4, 4, 1, 4><<<dim3(8, 16, 4), 256, 0, stream>>>(
      DBUF2, 1024, 1048576LL, 0LL, 0, DW2, 1024, 2097152LL, 0LL, 0,
      dec_b2, 2048LL, 0LL, nullptr, 0, 0, 0, DECO, 2048, 2097152LL, 0LL,
      nullptr, 0, 0, 0LL, 0LL, 1, 1024, 2048, 1024, 0, 0, 1);

  final_kernel<<<2048, 256, 0, stream>>>(DECO, MEAN, STD, out);
}

// Round 10
// 453.040 us; speedup vs baseline: 1.0311x; 1.0311x over previous
//
#include <hip/hip_runtime.h>
#include <hip/hip_bf16.h>
#include <math.h>

#define EPSF 1e-5f

typedef __attribute__((ext_vector_type(8))) short bf16x8;
typedef __attribute__((ext_vector_type(4))) float f32x4;

__device__ __forceinline__ void gld16(const void* g, void* l) {
  __builtin_amdgcn_global_load_lds(
      (const __attribute__((address_space(1))) unsigned int*)g,
      (__attribute__((address_space(3))) unsigned int*)l, 16, 0, 0);
}

// ---------------- fused instance-norm stats + normalize + transpose + hi/lo split ----------------
// x[b]: [512,32] -> XNB[b*32+c][l' hi | l'+512 lo]; also writes mean/std [B,32]
__global__ __launch_bounds__(256) void prep_kernel(
    const float* __restrict__ x, float* __restrict__ meanp,
    float* __restrict__ stdp, __hip_bfloat16* __restrict__ xnb)
{
  __shared__ float xs[512 * 33];
  __shared__ float red[8][32];
  __shared__ float red2[8][32];
  __shared__ float sm[32];
  __shared__ float srr[32];
  int b = blockIdx.x, tid = threadIdx.x;
  const float* xb = x + (size_t)b * 16384;
#pragma unroll
  for (int i = 0; i < 16; ++i) {
    int idx4 = tid + i * 256;
    int l = idx4 >> 3, c0 = (idx4 & 7) * 4;
    float4 v = *(const float4*)(xb + idx4 * 4);
    xs[l * 33 + c0 + 0] = v.x;
    xs[l * 33 + c0 + 1] = v.y;
    xs[l * 33 + c0 + 2] = v.z;
    xs[l * 33 + c0 + 3] = v.w;
  }
  __syncthreads();
  int c = tid & 31, ls = tid >> 5;
  float s = 0.f, s2 = 0.f;
  for (int l = ls; l < 512; l += 8) {
    float v = xs[l * 33 + c];
    s += v; s2 += v * v;
  }
  red[ls][c] = s; red2[ls][c] = s2;
  __syncthreads();
  if (ls == 0) {
#pragma unroll
    for (int i = 1; i < 8; ++i) { s += red[i][c]; s2 += red2[i][c]; }
    float m = s * (1.f / 512.f);
    float var = s2 * (1.f / 512.f) - m * m;
    float sd = sqrtf(var + EPSF);
    meanp[b * 32 + c] = m;
    stdp[b * 32 + c] = sd;
    sm[c] = m;
    srr[c] = 1.f / sd;
  }
  __syncthreads();
  for (int cc = 0; cc < 32; ++cc) {
    float m = sm[cc];
    float r = srr[cc];
    int l = tid * 2;
    float v0 = (xs[l * 33 + cc] - m) * r;
    float v1 = (xs[(l + 1) * 33 + cc] - m) * r;
    __hip_bfloat16 h0 = __float2bfloat16(v0);
    __hip_bfloat16 h1 = __float2bfloat16(v1);
    union { __hip_bfloat16 h[2]; unsigned int u; } H, L;
    H.h[0] = h0; H.h[1] = h1;
    L.h[0] = __float2bfloat16(v0 - __bfloat162float(h0));
    L.h[1] = __float2bfloat16(v1 - __bfloat162float(h1));
    unsigned int* dst =
        (unsigned int*)((unsigned short*)xnb + ((size_t)(b * 32 + cc)) * 1024 + l);
    dst[0] = H.u;
    dst[256] = L.u;
  }
}

// ---------------- Fourier-mask -> time-domain filter taps (duplicated) ----------------
// R6: table-driven (sig[257]+ctab[512] in LDS), 64 blocks; was 52.7us @ 8 blocks.
__global__ __launch_bounds__(256) void kfilt_kernel(
    const float* __restrict__ mw, float* __restrict__ kf)
{
  __shared__ float sig[257];
  __shared__ float ctab[512];
  __shared__ float red[8][33];
  int bid = blockIdx.x, tid = threadIdx.x;
  int nb = bid >> 4, t0 = (bid & 15) * 32;
  const float* m = mw + nb * 257;
  for (int i = tid; i < 257; i += 256) sig[i] = 1.f / (1.f + expf(-m[i]));
  ctab[tid]       = cosf(6.28318530717958647f * (float)tid * (1.f / 512.f));
  ctab[tid + 256] = cosf(6.28318530717958647f * (float)(tid + 256) * (1.f / 512.f));
  __syncthreads();
  int tl = tid & 31, fl = tid >> 5;
  int t = t0 + tl;
  float acc = 0.f;
#pragma unroll
  for (int j = 0; j < 32; ++j) {
    int f = fl * 32 + j;
    if (f >= 1) {
      int tf = (t * f) & 511;
      acc += 2.f * sig[f] * ctab[tf];
    }
  }
  red[fl][tl] = acc;
  __syncthreads();
  if (fl == 0) {
    float a = red[0][tl];
#pragma unroll
    for (int i = 1; i < 8; ++i) a += red[i][tl];
    float s0 = sig[0], sN = sig[256];
    a += s0 + ((t & 1) ? -sN : sN);
    float kv = a * (1.f / 512.f);
    kf[nb * 1024 + t] = kv;
    kf[nb * 1024 + t + 512] = kv;
  }
}

// ---------------- circulant matrix build: CM[nb][l][l' | l'+512] bf16 hi|lo ----------------
__global__ __launch_bounds__(256) void cmat_kernel(
    const float* __restrict__ kf, __hip_bfloat16* __restrict__ cm)
{
  int t = threadIdx.x;
  int row = blockIdx.x * 4 + (t >> 6);
  int nb = row >> 9, l = row & 511;
  int lp0 = (t & 63) * 8;
  union { __hip_bfloat16 h[8]; uint4 u; } H, L;
#pragma unroll
  for (int j = 0; j < 8; ++j) {
    float v = kf[nb * 1024 + 512 + l - (lp0 + j)];
    __hip_bfloat16 h = __float2bfloat16(v);
    H.h[j] = h;
    L.h[j] = __float2bfloat16(v - __bfloat162float(h));
  }
  unsigned short* dst = (unsigned short*)cm + (size_t)row * 1024 + lp0;
  *(uint4*)dst = H.u;
  *(uint4*)(dst + 512) = L.u;
}

// ---------------- fp32 -> bf16 hi/lo split: in [rows,K] -> out [rows,2K] ----------------
__global__ __launch_bounds__(256) void split_kernel(
    const float* __restrict__ in, __hip_bfloat16* __restrict__ out, int ks)
{
  int t = blockIdx.x * 256 + threadIdx.x;
  long long idx = (long long)t * 4;
  int K = 1 << ks;
  long long r = idx >> ks;
  int k = (int)(idx & (K - 1));
  float4 v = *(const float4*)(in + idx);
  float vv[4] = {v.x, v.y, v.z, v.w};
  union { __hip_bfloat16 h[4]; uint2 u; } H, L;
#pragma unroll
  for (int u = 0; u < 4; ++u) {
    H.h[u] = __float2bfloat16(vv[u]);
    L.h[u] = __float2bfloat16(vv[u] - __bfloat162float(H.h[u]));
  }
  unsigned short* ob = (unsigned short*)out + (r << (ks + 1)) + k;
  *(uint2*)ob = H.u;
  *(uint2*)(ob + K) = L.u;
}

// ---------------- fp32 -> bf16 hi-only cast (dense, single source) ----------------
__global__ __launch_bounds__(256) void splith_kernel(
    const float* __restrict__ in, __hip_bfloat16* __restrict__ out)
{
  long long idx = ((long long)blockIdx.x * 256 + threadIdx.x) * 4;
  float4 v = *(const float4*)(in + idx);
  union { __hip_bfloat16 h[4]; uint2 u; } H;
  H.h[0] = __float2bfloat16(v.x);
  H.h[1] = __float2bfloat16(v.y);
  H.h[2] = __float2bfloat16(v.z);
  H.h[3] = __float2bfloat16(v.w);
  *(uint2*)((unsigned short*)out + idx) = H.u;
}

// ---------------- fused hi-only cast of 4 weights into contiguous dest ----------------
// ranges (float4 units): enc_w2 524288 | wxh 262144 | dec_w1 524288 | dec_w2 2097152
__global__ __launch_bounds__(256) void splith4_kernel(
    const float* __restrict__ s0, const float* __restrict__ s1,
    const float* __restrict__ s2, const float* __restrict__ s3,
    __hip_bfloat16* __restrict__ out)
{
  long long i4 = (long long)blockIdx.x * 256 + threadIdx.x;  // 3,407,872 total
  const float* src;
  long long lo;
  if (i4 < 524288)        { src = s0; lo = i4; }
  else if (i4 < 786432)   { src = s1; lo = i4 - 524288; }
  else if (i4 < 1310720)  { src = s2; lo = i4 - 786432; }
  else                    { src = s3; lo = i4 - 1310720; }
  float4 v = ((const float4*)src)[lo];
  union { __hip_bfloat16 h[4]; uint2 u; } H;
  H.h[0] = __float2bfloat16(v.x);
  H.h[1] = __float2bfloat16(v.y);
  H.h[2] = __float2bfloat16(v.z);
  H.h[3] = __float2bfloat16(v.w);
  *(uint2*)((unsigned short*)out + i4 * 4) = H.u;
}

// ---------------- transpose + split: WT2[nb][col][hi 512 | lo 512] = whh^T ----------------
__global__ __launch_bounds__(256) void tsplit_kernel(
    const float* __restrict__ w, __hip_bfloat16* __restrict__ wt2)
{
  __shared__ float ts[64][65];
  int bx = blockIdx.x, by = blockIdx.y, nb = blockIdx.z;
  int t = threadIdx.x;
  int tr = t >> 4, c0 = (t & 15) * 4;
  const float* wb = w + (size_t)nb * 262144;
#pragma unroll
  for (int k = 0; k < 4; ++k) {
    int r = tr + k * 16;
    float4 v = *(const float4*)(wb + (size_t)(by * 64 + r) * 512 + bx * 64 + c0);
    ts[r][c0 + 0] = v.x; ts[r][c0 + 1] = v.y;
    ts[r][c0 + 2] = v.z; ts[r][c0 + 3] = v.w;
  }
  __syncthreads();
  unsigned short* ob = (unsigned short*)wt2 + (size_t)nb * 524288;
#pragma unroll
  for (int k = 0; k < 4; ++k) {
    int r = tr + k * 16;
    float vv[4] = {ts[c0][r], ts[c0 + 1][r], ts[c0 + 2][r], ts[c0 + 3][r]};
    union { __hip_bfloat16 h[4]; uint2 u; } H, L;
#pragma unroll
    for (int j = 0; j < 4; ++j) {
      H.h[j] = __float2bfloat16(vv[j]);
      L.h[j] = __float2bfloat16(vv[j] - __bfloat162float(H.h[j]));
    }
    size_t row = (size_t)(bx * 64 + r);
    *(uint2*)(ob + row * 1024 + by * 64 + c0) = H.u;
    *(uint2*)(ob + row * 1024 + 512 + by * 64 + c0) = L.u;
  }
}

// ---------------- split-bf16 MFMA GEMM, compile-time NSEG/NCH, tiled by template ----------------
// Tile = (32*NI) x (32*NJ), 256 thr (4 waves, 2x2). 16x16x32 bf16 MFMA.
// R9: per-site NCH, direct-A/B anchored:
//     enc1 (HBM/L3-streaming, 2 blocks/CU): NCH=2 (57.6) beats NCH=4 (90.8) — drain
//       exposure vs anti-phase co-resident block.
//     dec2: NCH=2 (R7=463.5 total) beats NCH=4 (R8=467.1) in single-variable A/B.
//     NSEG3 small-grid sites (128-256 blocks = 0.5-1 block/CU): NCH=4 — no co-resident
//       block exists, so drains are fully exposed either way; halving drain count
//       (8->4 barrier pairs at K=512) is a pure fixed-cost save. LDS 64KB, grid-limited.
//     <4,2> sites: NCH=4 (drove R5's net gain). conv: NCH=2 (4 blocks/CU).
// NSEG1: Ahi*Bhi   NSEG2: Ahi*(Bhi+Blo)   NSEG3: + Alo*Bhi
// swapg=1: blockIdx.x indexes M-tiles (XCD-local A stripes)
// R2: chunked-bijective XCD swizzle (T1): lid -> (lid%8)*(nwg/8)+lid/8
//     (FETCH 82->41MB measured at enc1). Identity fallback when nwg%8 != 0.
// z-batching two-level: off = (bz/nz2)*b?1 + (bz%nz2)*b?2 (element units).
// mode 0: normal epilogue (bias, Add fp32, relu, Cf fp32, C2 hi at ldc2 [+lo at loC2 if !=0])
// mode 1: XIH scatter (conv output, hi only)
// mode 2: Cf normal + C2 as XP concat [b][f*512+n | 4096+f*512+n]
template<int NI, int NJ, int NSEG, int NCH>
__global__ __launch_bounds__(256) void gemm_mfma(
    const __hip_bfloat16* __restrict__ A_, int ldA, long long bA1, long long bA2, int loA,
    const __hip_bfloat16* __restrict__ B_, int ldB, long long bB1, long long bB2, int loB,
    const float* __restrict__ bias, long long bBias1, long long bBias2,
    const float* __restrict__ Add, int ldadd, long long bAdd1, long long bAdd2,
    float* __restrict__ Cf, int ldcf, long long bCf1, long long bCf2,
    __hip_bfloat16* __restrict__ C2, int ldc2, int loC2, long long bC21, long long bC22,
    int nz2, int M, int N, int K, int relu, int mode, int swapg)
{
  constexpr bool three = (NSEG == 3);
  constexpr bool btwo = (NSEG >= 2);
  constexpr int CHA = 32 * NI * 32;   // chunk stride (shorts) for A buffers
  constexpr int CHB = 32 * NJ * 32;   // chunk stride (shorts) for B buffers
  __shared__ short sAh[NCH * 32 * NI * 32];
  __shared__ short sAl[three ? NCH * 32 * NI * 32 : 1];
  __shared__ short sBh[NCH * 32 * NJ * 32];
  __shared__ short sBl[btwo ? NCH * 32 * NJ * 32 : 1];

  // ---- R2: XCD-chunked block-index remap (pure reindex, no numeric effect) ----
  int gx = gridDim.x, gy = gridDim.y;
  int nwg = gx * gy * (int)gridDim.z;
  int lid = (int)blockIdx.x + gx * ((int)blockIdx.y + gy * (int)blockIdx.z);
  if ((nwg & 7) == 0) lid = (lid & 7) * (nwg >> 3) + (lid >> 3);
  int bz  = lid / (gx * gy);
  int rrm = lid - bz * (gx * gy);
  int byq = rrm / gx;
  int bxq = rrm - byq * gx;

  int z1 = bz / nz2, z2 = bz % nz2;
  const short* Ab = (const short*)A_ + (long long)z1 * bA1 + (long long)z2 * bA2;
  const short* Bb = (const short*)B_ + (long long)z1 * bB1 + (long long)z2 * bB2;
  int tid = threadIdx.x, wave = tid >> 6, lane = tid & 63;
  int bxv = swapg ? byq : bxq;
  int byv = swapg ? bxq : byq;
  int bm = byv * (32 * NI), bn = bxv * (32 * NJ);
  int wrow = (wave >> 1) * (16 * NI), wcol = (wave & 1) * (16 * NJ);

  int sr = lane >> 2;
  int qg = (lane & 3) ^ (sr & 3);
  int arA = wave * 8 * NI;
  int arB = wave * 8 * NJ;

  f32x4 acc[NI][NJ];
#pragma unroll
  for (int i = 0; i < NI; ++i)
#pragma unroll
    for (int j = 0; j < NJ; ++j)
      acc[i][j] = (f32x4){0.f, 0.f, 0.f, 0.f};

  int frow = lane & 15;
  int fq = lane >> 4;
  int aoffs[NI], boffs[NJ];
#pragma unroll
  for (int i = 0; i < NI; ++i) {
    int ra = wrow + 16 * i + frow;
    aoffs[i] = ra * 32 + ((fq ^ (ra & 3)) << 3);
  }
#pragma unroll
  for (int j = 0; j < NJ; ++j) {
    int rb = wcol + 16 * j + frow;
    boffs[j] = rb * 32 + ((fq ^ (rb & 3)) << 3);
  }

  const short* Ah = Ab + (long long)(bm + arA + sr) * ldA + qg * 8;
  const short* Al = Ah + loA;
  const short* Bh = Bb + (long long)(bn + arB + sr) * ldB + qg * 8;
  const short* Bl = Bh + loB;

  for (int ko = 0; ko < K; ko += 32 * NCH) {
    // stage NCH 32-K chunks (chunk ch at +32*ch K, into LDS offset ch*CHA/CHB)
#pragma unroll
    for (int cc = 0; cc < NI / 2; ++cc) {
#pragma unroll
      for (int ch = 0; ch < NCH; ++ch) {
        gld16(Ah + ko + ch * 32 + cc * 16 * ldA, &sAh[ch * CHA + (arA + cc * 16) * 32]);
        if constexpr (three)
          gld16(Al + ko + ch * 32 + cc * 16 * ldA, &sAl[ch * CHA + (arA + cc * 16) * 32]);
      }
    }
#pragma unroll
    for (int cc = 0; cc < NJ / 2; ++cc) {
#pragma unroll
      for (int ch = 0; ch < NCH; ++ch) {
        gld16(Bh + ko + ch * 32 + cc * 16 * ldB, &sBh[ch * CHB + (arB + cc * 16) * 32]);
        if constexpr (btwo)
          gld16(Bl + ko + ch * 32 + cc * 16 * ldB, &sBl[ch * CHB + (arB + cc * 16) * 32]);
      }
    }
    __syncthreads();
#pragma unroll
    for (int h = 0; h < NCH; ++h) {
      const int oA = h * CHA, oB = h * CHB;
      bf16x8 ah[NI], al[NI], bh[NJ], bl[NJ];
#pragma unroll
      for (int i = 0; i < NI; ++i) ah[i] = *(const bf16x8*)&sAh[oA + aoffs[i]];
#pragma unroll
      for (int j = 0; j < NJ; ++j) bh[j] = *(const bf16x8*)&sBh[oB + boffs[j]];
      if constexpr (btwo) {
#pragma unroll
        for (int j = 0; j < NJ; ++j) bl[j] = *(const bf16x8*)&sBl[oB + boffs[j]];
      }
      if constexpr (three) {
#pragma unroll
        for (int i = 0; i < NI; ++i) al[i] = *(const bf16x8*)&sAl[oA + aoffs[i]];
      }
#pragma unroll
      for (int i = 0; i < NI; ++i)
#pragma unroll
        for (int j = 0; j < NJ; ++j) {
          acc[i][j] = __builtin_amdgcn_mfma_f32_16x16x32_bf16(ah[i], bh[j], acc[i][j], 0, 0, 0);
          if constexpr (btwo)
            acc[i][j] = __builtin_amdgcn_mfma_f32_16x16x32_bf16(ah[i], bl[j], acc[i][j], 0, 0, 0);
          if constexpr (three)
            acc[i][j] = __builtin_amdgcn_mfma_f32_16x16x32_bf16(al[i], bh[j], acc[i][j], 0, 0, 0);
        }
    }
    __syncthreads();
  }

  short* c2z = C2 ? (short*)C2 + (long long)z1 * bC21 + (long long)z2 * bC22 : nullptr;

  if (mode == 1) {
    // m = l (0..511), n = b*32+c -> XIH row = b*8 + l/64, col = (l%64)*32 + c
#pragma unroll
    for (int j = 0; j < NJ; ++j) {
      int n = bn + wcol + 16 * j + frow;
      int bidx = n >> 5, c = n & 31;
#pragma unroll
      for (int i = 0; i < NI; ++i)
#pragma unroll
        for (int r = 0; r < 4; ++r) {
          int m = bm + wrow + 16 * i + fq * 4 + r;
          int row = bidx * 8 + (m >> 6);
          int col = (m & 63) * 32 + c;
          ((__hip_bfloat16*)c2z)[(long long)row * 2048 + col] =
              __float2bfloat16(acc[i][j][r]);
        }
    }
    return;
  }

  const float* biasz = bias ? bias + (long long)z1 * bBias1 + (long long)z2 * bBias2 : nullptr;
  const float* addz  = Add  ? Add  + (long long)z1 * bAdd1  + (long long)z2 * bAdd2  : nullptr;
  float* cfz = Cf ? Cf + (long long)z1 * bCf1 + (long long)z2 * bCf2 : nullptr;

#pragma unroll
  for (int j = 0; j < NJ; ++j) {
    int n = bn + wcol + 16 * j + frow;
    float bv = biasz ? biasz[n] : 0.f;
#pragma unroll
    for (int i = 0; i < NI; ++i) {
#pragma unroll
      for (int r = 0; r < 4; ++r) {
        int m = bm + wrow + 16 * i + fq * 4 + r;
        float v = acc[i][j][r] + bv;
        if (addz) v += addz[(long long)m * ldadd + n];
        if (relu) v = fmaxf(v, 0.f);
        if (cfz) cfz[(long long)m * ldcf + n] = v;
        if (c2z) {
          __hip_bfloat16 h = __float2bfloat16(v);
          if (mode == 2) {
            __hip_bfloat16 l = __float2bfloat16(v - __bfloat162float(h));
            long long off = (long long)(m >> 3) * 8192 + (m & 7) * 512 + n;
            ((__hip_bfloat16*)c2z)[off] = h;
            ((__hip_bfloat16*)c2z)[off + 4096] = l;
          } else {
            ((__hip_bfloat16*)c2z)[(long long)m * ldc2 + n] = h;
            if (loC2) {
              __hip_bfloat16 l = __float2bfloat16(v - __bfloat162float(h));
              ((__hip_bfloat16*)c2z)[(long long)m * ldc2 + loC2 + n] = l;
            }
          }
        }
      }
    }
  }
}

// ---------------- LayerNorm over 512, writes bf16 hi-only [row, 512] ----------------
__global__ __launch_bounds__(256) void ln_kernel(
    const float* __restrict__ p, const float* __restrict__ g,
    const float* __restrict__ bb, __hip_bfloat16* __restrict__ p2)
{
  int row = blockIdx.x;              // NB*B*4 = 4096
  int nb = row >> 10;
  const float* pr = p + (size_t)row * 512;
  int tid = threadIdx.x;
  float v0 = pr[tid], v1 = pr[tid + 256];
  float s = v0 + v1, s2 = v0 * v0 + v1 * v1;
#pragma unroll
  for (int o = 32; o > 0; o >>= 1) {
    s += __shfl_down(s, o);
    s2 += __shfl_down(s2, o);
  }
  __shared__ float rs[4];
  __shared__ float rs2[4];
  int w = tid >> 6;
  if ((tid & 63) == 0) { rs[w] = s; rs2[w] = s2; }
  __syncthreads();
  s = rs[0] + rs[1] + rs[2] + rs[3];
  s2 = rs2[0] + rs2[1] + rs2[2] + rs2[3];
  float mval = s * (1.f / 512.f);
  float var = s2 * (1.f / 512.f) - mval * mval;
  float r = 1.f / sqrtf(var + EPSF);
  const float* gn = g + nb * 512;
  const float* bn = bb + nb * 512;
  float y0 = (v0 - mval) * r * gn[tid] + bn[tid];
  float y1 = (v1 - mval) * r * gn[tid + 256] + bn[tid + 256];
  __hip_bfloat16* o2 = p2 + (size_t)nb * 524288 + (size_t)(row & 1023) * 512;
  o2[tid] = __float2bfloat16(y0);
  o2[tid + 256] = __float2bfloat16(y1);
}

// ---------------- final: out = (sum_nb deco) * std + mean ----------------
__global__ __launch_bounds__(256) void final_kernel(
    const float* __restrict__ deco, const float* __restrict__ meanp,
    const float* __restrict__ stdp, float* __restrict__ out)
{
  int t = blockIdx.x * 256 + threadIdx.x;
  int b = t >> 11;
  int r = t & 2047;
  int p = (r >> 3) & 63;
  int cq = r & 7;
  size_t base = ((size_t)(b * 4 + (r >> 9))) * 2048 + p * 32 + cq * 4;
  const size_t nbs = 1024ull * 2048ull;
  float4 a0 = *(const float4*)(deco + base);
  float4 a1 = *(const float4*)(deco + nbs + base);
  float4 a2 = *(const float4*)(deco + 2 * nbs + base);
  float4 a3 = *(const float4*)(deco + 3 * nbs + base);
  float4 m4 = *(const float4*)(meanp + b * 32 + cq * 4);
  float4 s4 = *(const float4*)(stdp + b * 32 + cq * 4);
  float4 o;
  o.x = (a0.x + a1.x + a2.x + a3.x) * s4.x + m4.x;
  o.y = (a0.y + a1.y + a2.y + a3.y) * s4.y + m4.y;
  o.z = (a0.z + a1.z + a2.z + a3.z) * s4.z + m4.z;
  o.w = (a0.w + a1.w + a2.w + a3.w) * s4.w + m4.w;
  *(float4*)(out + (size_t)t * 4) = o;
}

extern "C" void kernel_launch(void* const* d_in, const int* in_sizes, int n_in,
                              void* d_out, int out_size, void* d_ws, size_t ws_size,
                              hipStream_t stream) {
  const float* x_enc  = (const float*)d_in[0];
  const float* mask_w = (const float*)d_in[4];
  const float* enc_w1 = (const float*)d_in[5];
  const float* enc_b1 = (const float*)d_in[6];
  const float* enc_w2 = (const float*)d_in[7];
  const float* enc_b2 = (const float*)d_in[8];
  const float* wxh    = (const float*)d_in[9];
  const float* whh    = (const float*)d_in[10];
  const float* ln_g   = (const float*)d_in[11];
  const float* ln_b   = (const float*)d_in[12];
  const float* dec_w1 = (const float*)d_in[13];
  const float* dec_b1 = (const float*)d_in[14];
  const float* dec_w2 = (const float*)d_in[15];
  const float* dec_b2 = (const float*)d_in[16];
  float* out = (float*)d_out;

  typedef __hip_bfloat16 bf;
  char* W = (char*)d_ws;
  float* MEAN = (float*)(W);
  float* STD  = (float*)(W + 32768);
  float* KF   = (float*)(W + 98304);
  char* B0 = W + 131072;
  // ---- layout (MB offsets from B0); peak 112 MB; lifetimes as R9 (verified) ----
  bf* XIH   = (bf*)(B0);                    // [0,32)    dead after enc1
  bf* XNB   = (bf*)(B0 + 33554432);         // [32,48)   dead after conv
  bf* CM    = (bf*)(B0 + 50331648);         // [48,52)   dead after conv
  bf* WW    = (bf*)(B0 + 33554432);         // [32,48)   16MB hi, written post-conv, dead after enc1
  bf* ENCB2 = (bf*)(B0 + 67108864);         // [64,80)   16MB hi, dead after enc2
  // weight splits (after enc1; splith4 dest = [0,26) contiguous):
  bf* EW2   = (bf*)(B0);                    // [0,4)     4MB hi
  bf* WXH2  = (bf*)(B0 + 4194304);          // [4,6)     2MB hi
  bf* DW1   = (bf*)(B0 + 6291456);          // [6,10)    4MB hi, read at dec1
  bf* DW2   = (bf*)(B0 + 10485760);         // [10,26)   16MB hi, read at dec2
  bf* WSP   = (bf*)(B0 + 27262976);         // [26,30)   4MB hi|lo
  bf* W2SP  = (bf*)(B0 + 31457280);         // [30,34)   4MB hi|lo
  bf* WTSP  = (bf*)(B0 + 35651584);         // [34,38)   4MB hi|lo, dead after W2 GEMM
  bf* ENC22 = (bf*)(B0 + 39845888);         // [38,46)   8MB hi, dead after xp
  float* XP = (float*)(B0 + 48234496);      // [46,62)   fp32, dead after y-combine
  bf* XP2   = (bf*)(B0 + 67108864);         // [64,80)   hi|lo (ENCB2 dead), dead after y-combine
  float* YF = (float*)(B0 + 83886080);      // [80,88)   dead after Horner-3
  bf* Y2    = (bf*)(B0 + 92274688);         // [88,96)   hi|lo, dead after Horner-1
  bf* H2    = (bf*)(B0 + 100663296);        // [96,98)
  bf* H22   = (bf*)(B0 + 102760448);        // [98,100)
  bf* P12   = (bf*)(B0 + 104857600);        // [100,104)
  float* PREDS = (float*)(B0 + 109051904);  // [104,112)
  bf* PREDS2 = (bf*)(B0);                   // [0,4)     written at ln (EW2 dead)
  bf* DBUF2 = (bf*)(B0 + 83886080);         // [80,88)   dec1 out (YF dead)
  float* DECO = (float*)(B0 + 33554432);    // [32,64)   dec2 out (WTSP/ENC22/XP dead)

  prep_kernel<<<256, 256, 0, stream>>>(x_enc, MEAN, STD, XNB);
  kfilt_kernel<<<64, 256, 0, stream>>>(mask_w, KF);
  cmat_kernel<<<512, 256, 0, stream>>>(KF, CM);

  // conv as MFMA GEMM (pure bf16 hi, NSEG=1, NCH=2: grid 1024 = 4 blocks/CU, keep 32KB LDS)
  gemm_mfma<4, 4, 1, 2><<<dim3(64, 4, 4), 256, 0, stream>>>(
      CM, 1024, 524288LL, 0LL, 0, XNB, 1024, 0LL, 0LL, 0,
      nullptr, 0, 0, nullptr, 0, 0, 0, nullptr, 0, 0, 0,
      XIH, 0, 0, 4194304LL, 0LL, 1, 512, 8192, 512, 0, 1, 0);

  // enc1: M=2048 N=1024 K=2048, NSEG=1, NCH=2 (HBM-streaming site: NCH=4 regressed 57.6->90.8)
  splith_kernel<<<8192, 256, 0, stream>>>(enc_w1, WW);
  gemm_mfma<4, 4, 1, 2><<<dim3(16, 8, 4), 256, 0, stream>>>(
      XIH, 2048, 4194304LL, 0LL, 0, WW, 2048, 2097152LL, 0LL, 0,
      enc_b1, 1024LL, 0LL, nullptr, 0, 0, 0, nullptr, 0, 0, 0,
      ENCB2, 1024, 0, 2097152LL, 0LL, 1, 2048, 1024, 2048, 1, 0, 1);

  // fused weight casts (XIH dead now): enc_w2|wxh|dec_w1|dec_w2 -> [0,26)
  splith4_kernel<<<13312, 256, 0, stream>>>(enc_w2, wxh, dec_w1, dec_w2, EW2);
  split_kernel<<<1024, 256, 0, stream>>>(whh, WSP, 9);
  tsplit_kernel<<<dim3(8, 8, 4), 256, 0, stream>>>(whh, WTSP);

  // enc2: M=2048 N=512 K=1024, NSEG=1, NCH=4 (48KB LDS, 24KB burst); swapg
  gemm_mfma<4, 2, 1, 4><<<dim3(16, 8, 4), 256, 0, stream>>>(
      ENCB2, 1024, 2097152LL, 0LL, 0, EW2, 1024, 524288LL, 0LL, 0,
      enc_b2, 512LL, 0LL, nullptr, 0, 0, 0, nullptr, 0, 0, 0,
      ENC22, 512, 0, 1048576LL, 0LL, 1, 2048, 512, 1024, 0, 0, 1);

  // xp = enc2 @ wxh^T: NSEG=1, NCH=4; fp32 out + XP2 hi|lo-concat (mode 2); swapg
  gemm_mfma<4, 2, 1, 4><<<dim3(16, 8, 4), 256, 0, stream>>>(
      ENC22, 512, 1048576LL, 0LL, 0, WXH2, 512, 262144LL, 0LL, 0,
      nullptr, 0, 0, nullptr, 0, 0, 0, XP, 512, 1048576LL, 0LL,
      XP2, 0, 0, 2097152LL, 0LL, 1, 2048, 512, 512, 0, 2, 1);

  // W2 = W @ W (NSEG=3, NCH=4: 64KB LDS, grid 256 = 1 block/CU -> drain-count halving is free)
  gemm_mfma<2, 2, 3, 4><<<dim3(8, 8, 4), 256, 0, stream>>>(
      WSP, 1024, 524288LL, 0LL, 512, WTSP, 1024, 524288LL, 0LL, 512,
      nullptr, 0, 0, nullptr, 0, 0, 0, nullptr, 0, 0, 0,
      W2SP, 1024, 512, 524288LL, 0LL, 1, 512, 512, 512, 0, 0, 0);

  // y_j = xp_{2j} @ W^T + xp_{2j+1}   (z1 = j, z2 = nb, 16 total), NSEG=3, NCH=4
  gemm_mfma<2, 2, 3, 4><<<dim3(8, 4, 16), 256, 0, stream>>>(
      XP2, 8192, 1024LL, 2097152LL, 4096, WSP, 1024, 0LL, 524288LL, 512,
      nullptr, 0, 0, XP + 512, 4096, 1024LL, 1048576LL,
      YF, 512, 524288LL, 131072LL,
      Y2, 1024, 512, 1048576LL, 262144LL, 4, 256, 512, 512, 0, 0, 0);

  // Horner with W2 (NSEG=3, NCH=4: grid 128 = 0.5 block/CU, latency-dominated)
  gemm_mfma<2, 2, 3, 4><<<dim3(8, 4, 4), 256, 0, stream>>>(
      Y2, 1024, 0LL, 262144LL, 512, W2SP, 1024, 0LL, 524288LL, 512,
      nullptr, 0, 0, YF + 524288, 512, 0LL, 131072LL, nullptr, 0, 0, 0,
      H2, 1024, 512, 0LL, 262144LL, 4, 256, 512, 512, 0, 0, 0);
  gemm_mfma<2, 2, 3, 4><<<dim3(8, 4, 4), 256, 0, stream>>>(
      H2, 1024, 0LL, 262144LL, 512, W2SP, 1024, 0LL, 524288LL, 512,
      nullptr, 0, 0, YF + 1048576, 512, 0LL, 131072LL, nullptr, 0, 0, 0,
      H22, 1024, 512, 0LL, 262144LL, 4, 256, 512, 512, 0, 0, 0);
  gemm_mfma<2, 2, 3, 4><<<dim3(8, 4, 4), 256, 0, stream>>>(
      H22, 1024, 0LL, 262144LL, 512, W2SP, 1024, 0LL, 524288LL, 512,
      nullptr, 0, 0, YF + 1572864, 512, 0LL, 131072LL, nullptr, 0, 0, 0,
      H2, 1024, 512, 0LL, 262144LL, 4, 256, 512, 512, 0, 0, 0);

  // free-run A: p1 = h@W^T (z1=0), p2 = h@W2^T (z1=1), NSEG=3, NCH=4
  gemm_mfma<2, 2, 3, 4><<<dim3(8, 4, 8), 256, 0, stream>>>(
      H2, 1024, 0LL, 262144LL, 512, WSP, 1024, 2097152LL, 524288LL, 512,
      nullptr, 0, 0, nullptr, 0, 0, 0, PREDS, 2048, 512LL, 524288LL,
      P12, 1024, 512, 1048576LL, 262144LL, 4, 256, 512, 512, 0, 0, 0);
  // free-run B: p3 = p1@W2^T, p4 = p2@W2^T, NSEG=3, NCH=4
  gemm_mfma<2, 2, 3, 4><<<dim3(8, 4, 8), 256, 0, stream>>>(
      P12, 1024, 1048576LL, 262144LL, 512, W2SP, 1024, 0LL, 524288LL, 512,
      nullptr, 0, 0, nullptr, 0, 0, 0, PREDS + 1024, 2048, 512LL, 524288LL,
      nullptr, 0, 0, 0LL, 0LL, 4, 256, 512, 512, 0, 0, 0);

  ln_kernel<<<4096, 256, 0, stream>>>(PREDS, ln_g, ln_b, PREDS2);

  // dec1: M=1024 N=1024 K=512, NSEG=1, NCH=4 (48KB LDS)
  gemm_mfma<4, 2, 1, 4><<<dim3(16, 8, 4), 256, 0, stream>>>(
      PREDS2, 512, 524288LL, 0LL, 0, DW1, 512, 524288LL, 0LL, 0,
      dec_b1, 1024LL, 0LL, nullptr, 0, 0, 0, nullptr, 0, 0, 0,
      DBUF2, 1024, 0, 1048576LL, 0LL, 1, 1024, 1024, 512, 1, 0, 0);
  // dec2: M=1024 N=2048 K=1024, NSEG=1, NCH=2 (R7 vs R8 direct A/B: NCH=2 better by 3.6us);
  //       swapg + (8,16,4) L2-chunk grid
  gemm_mfma<4, 4, 1, 2><<<dim3(8, 16, 4), 256, 0, stream>>>(
      DBUF2, 1024, 1048576LL, 0LL, 0, DW2, 1024, 2097152LL, 0LL, 0,
      dec_b2, 2048LL, 0LL, nullptr, 0, 0, 0, DECO, 2048, 2097152LL, 0LL,
      nullptr, 0, 0, 0LL, 0LL, 1, 1024, 2048, 1024, 0, 0, 1);

  final_kernel<<<2048, 256, 0, stream>>>(DECO, MEAN, STD, out);
}